// Round 16
// baseline (106.493 us; speedup 1.0000x reference)
//
#include <hip/hip_runtime.h>

#define LN 1024
#define FF 128
#define HH 128
#define CC 10
#define DD 34314
#define DD2 17157
#define CHK 2145
#define OFF_W0 0
#define OFF_B0 16384
#define OFF_W1 16512
#define OFF_B1 32896
#define OFF_W2 33024
#define OFF_B2 34304

__global__ void init_delta(float* delta) { *delta = 0.f; }

__device__ __forceinline__ float invmut(const float* h, int node, int par) {
    return 1.f / fmaxf(fabsf(h[node] - h[par]), 1e-7f);
}

// ---------------- P1: eff5[n5] = sum of rows on path level5(n5) .. root (R14, unchanged) --------
__global__ __launch_bounds__(1024) void eff5_kernel(const float* __restrict__ W,
                                                    const float* __restrict__ heights,
                                                    float* __restrict__ eff,
                                                    float* __restrict__ delta_out) {
    const int bid = blockIdx.x;
    const int n5  = bid >> 3;
    const int ck  = bid & 7;
    const int tid = threadIdx.x, lane = tid & 63, wv = tid >> 6;

    int p[6];
    p[0] = 31 + n5;
#pragma unroll
    for (int k = 1; k < 6; ++k) p[k] = (p[k - 1] - 1) >> 1;

    const float2* S[6];
#pragma unroll
    for (int k = 0; k < 6; ++k) S[k] = reinterpret_cast<const float2*>(W + (size_t)p[k] * DD);
    float2* E = reinterpret_cast<float2*>(eff + (size_t)n5 * DD);

    float wgt[6];
#pragma unroll
    for (int k = 0; k < 5; ++k)
        wgt[k] = ((n5 & ((1 << k) - 1)) == 0) ? invmut(heights, p[k], p[k + 1]) : 0.f;
    wgt[5] = 0.f;
    const float sqm = (n5 == 0) ? 1.f : 0.f;

    float dacc = 0.f, sacc = 0.f;
    const int lo = ck * CHK;
    const int hi = min(lo + CHK, DD2);
#pragma unroll 1
    for (int i = lo + tid; i < hi; i += 1024) {
        float ex = 0.f, ey = 0.f;
#pragma unroll
        for (int k = 0; k < 6; ++k) {
            const float2 w = S[k][i];
            ex += w.x; ey += w.y;
            dacc += (fabsf(w.x) + fabsf(w.y)) * wgt[k];
            if (k == 5) sacc += w.x * w.x + w.y * w.y;
        }
        E[i] = make_float2(ex, ey);
    }

    __shared__ float red[16];
    float v = dacc + sacc * sqm;
    for (int o = 32; o > 0; o >>= 1) v += __shfl_down(v, o);
    if (lane == 0) red[wv] = v;
    __syncthreads();
    if (tid == 0) {
        float s = 0.f;
#pragma unroll
        for (int w = 0; w < 16; ++w) s += red[w];
        atomicAdd(delta_out, s);
    }
}

// Common per-subtree stream/weight setup (10 streams: E, l8, l7, l6, 2xl9, 4xleaf).
#define SETUP_STREAMS()                                                               \
    const int l8 = 255 + m;                                                           \
    const int l7 = (l8 - 1) >> 1;                                                     \
    const int l6 = (l7 - 1) >> 1;                                                     \
    const int l5 = (l6 - 1) >> 1;                                                     \
    const float* RE = eff + (size_t)(m >> 3) * DD;                                    \
    const float* RP[3];                                                               \
    RP[0] = W + (size_t)l8 * DD;                                                      \
    RP[1] = W + (size_t)l7 * DD;                                                      \
    RP[2] = W + (size_t)l6 * DD;                                                      \
    const int n9a = 511 + 2 * m, n9b = n9a + 1;                                       \
    const float* RA[2];                                                               \
    RA[0] = W + (size_t)n9a * DD;                                                     \
    RA[1] = W + (size_t)n9b * DD;                                                     \
    const float* RB[4];                                                               \
    _Pragma("unroll")                                                                 \
    for (int q = 0; q < 4; ++q) RB[q] = W + (size_t)(1023 + 4 * m + q) * DD;          \
    float wgtP[3];                                                                    \
    wgtP[0] = invmut(heights, l8, l7);                                                \
    wgtP[1] = ((m & 1) == 0) ? invmut(heights, l7, l6) : 0.f;                         \
    wgtP[2] = ((m & 3) == 0) ? invmut(heights, l6, l5) : 0.f;                         \
    float wgtA[2];                                                                    \
    wgtA[0] = invmut(heights, n9a, l8);                                               \
    wgtA[1] = invmut(heights, n9b, l8);                                               \
    float wgtB[4];                                                                    \
    _Pragma("unroll")                                                                 \
    for (int q = 0; q < 4; ++q)                                                       \
        wgtB[q] = invmut(heights, 1023 + 4 * m + q, (q < 2) ? n9a : n9b);

// ---------------- K1/K2: one layer, output-column-half split ----------------
// 512 blocks = (m, ch); __launch_bounds__(1024,8) -> <=64 VGPR, 2 blocks/CU, 32 waves/CU.
// Inner loop = R14's proven unroll-2 10-stream pattern on the 64-col half.
template <int OFFW, int OFFB>
__global__ __launch_bounds__(1024, 8) void layer_split(const float* __restrict__ W,
                                                       const float* __restrict__ eff,
                                                       const float* __restrict__ invec,
                                                       const float* __restrict__ heights,
                                                       float* __restrict__ outvec,
                                                       float* __restrict__ delta_out) {
    const int bid = blockIdx.x;
    const int u   = ((bid & 7) << 6) | (bid >> 3);    // XCD-chunked bijection (512 = 8*64)
    const int m   = u >> 1;
    const int ch  = u & 1;
    const int tid = threadIdx.x, lane = tid & 63, wv = tid >> 6;
    const int fs  = tid >> 5;                         // 0..31 f-slot
    const int cp  = tid & 31;                         // float2 col within half

    SETUP_STREAMS();

    __shared__ float ins[4][FF];
    __shared__ float part[4][32][64];                 // 32 KB
    __shared__ float red[16];

    if (tid < 512) { const int q = tid >> 7, t = tid & 127; ins[q][t] = invec[(4 * m + q) * FF + t]; }

    float dacc = 0.f;
    __syncthreads();

    const float2* SE = reinterpret_cast<const float2*>(RE + OFFW);
    const float2* SP[3];
#pragma unroll
    for (int r = 0; r < 3; ++r) SP[r] = reinterpret_cast<const float2*>(RP[r] + OFFW);
    const float2* SA[2];
#pragma unroll
    for (int r = 0; r < 2; ++r) SA[r] = reinterpret_cast<const float2*>(RA[r] + OFFW);
    const float2* SB[4];
#pragma unroll
    for (int r = 0; r < 4; ++r) SB[r] = reinterpret_cast<const float2*>(RB[r] + OFFW);

    float yx[4] = {0.f, 0.f, 0.f, 0.f}, yy[4] = {0.f, 0.f, 0.f, 0.f};

#pragma unroll 2
    for (int it = 0; it < 4; ++it) {
        const int f   = it * 32 + fs;
        const int off = (f << 6) + (ch << 5) + cp;
        const float2 we = SE[off];
        float ex = we.x, ey = we.y;
#pragma unroll
        for (int k = 0; k < 3; ++k) {
            const float2 w = SP[k][off];
            ex += w.x; ey += w.y;
            dacc += (fabsf(w.x) + fabsf(w.y)) * wgtP[k];
        }
        const float2 wa0 = SA[0][off];
        const float2 wa1 = SA[1][off];
        dacc += (fabsf(wa0.x) + fabsf(wa0.y)) * wgtA[0];
        dacc += (fabsf(wa1.x) + fabsf(wa1.y)) * wgtA[1];
#pragma unroll
        for (int q = 0; q < 4; ++q) {
            const float2 wb = SB[q][off];
            dacc += (fabsf(wb.x) + fabsf(wb.y)) * wgtB[q];
            const float2 wa = (q < 2) ? wa0 : wa1;
            const float xv = ins[q][f];
            yx[q] += xv * (ex + wa.x + wb.x);
            yy[q] += xv * (ey + wa.y + wb.y);
        }
    }
#pragma unroll
    for (int q = 0; q < 4; ++q)
        *reinterpret_cast<float2*>(&part[q][fs][2 * cp]) = make_float2(yx[q], yy[q]);
    __syncthreads();

    if (tid < 256) {                                  // q = tid>>6 is wave-uniform
        const int q = tid >> 6, col = tid & 63;
        const int gcol = ch * 64 + col;
        const float p0 = RP[0][OFFB + gcol];
        const float p1 = RP[1][OFFB + gcol];
        const float p2 = RP[2][OFFB + gcol];
        float eb = RE[OFFB + gcol] + p0 + p1 + p2;
        if (q == 0)
            dacc += fabsf(p0) * wgtP[0] + fabsf(p1) * wgtP[1] + fabsf(p2) * wgtP[2];
        const float a0 = RA[0][OFFB + gcol];
        const float a1 = RA[1][OFFB + gcol];
        if (q == 0) dacc += fabsf(a0) * wgtA[0];
        if (q == 2) dacc += fabsf(a1) * wgtA[1];
        const float bq = RB[q][OFFB + gcol];
        dacc += fabsf(bq) * wgtB[q];
        float s = eb + ((q < 2) ? a0 : a1) + bq;
#pragma unroll
        for (int g = 0; g < 32; ++g) s += part[q][g][col];
        outvec[(4 * m + q) * HH + gcol] = fmaxf(s, 0.f);
    }

    float v = dacc;
    for (int o = 32; o > 0; o >>= 1) v += __shfl_down(v, o);
    if (lane == 0) red[wv] = v;
    __syncthreads();
    if (tid == 0) {
        float s = 0.f;
#pragma unroll
        for (int w = 0; w < 16; ++w) s += red[w];
        atomicAdd(delta_out, s);
    }
}

// ---------------- K3: layer 2 + softmax + W2/b2 delta (R14 layer-2 section) ----------------
__global__ __launch_bounds__(1024, 4) void head_kernel(const float* __restrict__ W,
                                                       const float* __restrict__ eff,
                                                       const float* __restrict__ ws_h1,
                                                       const float* __restrict__ heights,
                                                       float* __restrict__ out,
                                                       float* __restrict__ delta_out) {
    const int bid = blockIdx.x;
    const int m   = ((bid & 7) << 5) | (bid >> 3);    // 256 = 8*32
    const int tid = threadIdx.x, lane = tid & 63, wv = tid >> 6;

    SETUP_STREAMS();

    __shared__ float ins[4][HH];
    __shared__ float lgts[4][CC];
    __shared__ float red[16];

    if (tid < 512) { const int q = tid >> 7, t = tid & 127; ins[q][t] = ws_h1[(4 * m + q) * HH + t]; }
    if (tid < 4 * CC) ((float*)lgts)[tid] = 0.f;

    float dacc = 0.f;
    __syncthreads();

    {
        const float2* SE = reinterpret_cast<const float2*>(RE + OFF_W2);
        const float2* SP[3];
#pragma unroll
        for (int r = 0; r < 3; ++r) SP[r] = reinterpret_cast<const float2*>(RP[r] + OFF_W2);
        const float2* SA[2];
#pragma unroll
        for (int r = 0; r < 2; ++r) SA[r] = reinterpret_cast<const float2*>(RA[r] + OFF_W2);
        const float2* SB[4];
#pragma unroll
        for (int r = 0; r < 4; ++r) SB[r] = reinterpret_cast<const float2*>(RB[r] + OFF_W2);
        if (tid < 640) {
            const int h  = tid / 5;
            const int c0 = (tid - 5 * h) * 2;
            const float2 we = SE[tid];
            float ex = we.x, ey = we.y;
#pragma unroll
            for (int k = 0; k < 3; ++k) {
                const float2 w = SP[k][tid];
                ex += w.x; ey += w.y;
                dacc += (fabsf(w.x) + fabsf(w.y)) * wgtP[k];
            }
            const float2 wa0 = SA[0][tid];
            const float2 wa1 = SA[1][tid];
            dacc += (fabsf(wa0.x) + fabsf(wa0.y)) * wgtA[0];
            dacc += (fabsf(wa1.x) + fabsf(wa1.y)) * wgtA[1];
#pragma unroll
            for (int q = 0; q < 4; ++q) {
                const float2 wb = SB[q][tid];
                dacc += (fabsf(wb.x) + fabsf(wb.y)) * wgtB[q];
                const float2 wa = (q < 2) ? wa0 : wa1;
                const float hv = ins[q][h];
                atomicAdd(&lgts[q][c0],     hv * (ex + wa.x + wb.x));
                atomicAdd(&lgts[q][c0 + 1], hv * (ey + wa.y + wb.y));
            }
        }
        __syncthreads();
        if (tid < CC) {
            const float p0 = RP[0][OFF_B2 + tid];
            const float p1 = RP[1][OFF_B2 + tid];
            const float p2 = RP[2][OFF_B2 + tid];
            float eb = RE[OFF_B2 + tid] + p0 + p1 + p2;
            dacc += fabsf(p0) * wgtP[0] + fabsf(p1) * wgtP[1] + fabsf(p2) * wgtP[2];
            const float a0 = RA[0][OFF_B2 + tid];
            const float a1 = RA[1][OFF_B2 + tid];
            dacc += fabsf(a0) * wgtA[0] + fabsf(a1) * wgtA[1];
#pragma unroll
            for (int q = 0; q < 4; ++q) {
                const float bq = RB[q][OFF_B2 + tid];
                dacc += fabsf(bq) * wgtB[q];
                lgts[q][tid] += eb + ((q < 2) ? a0 : a1) + bq;
            }
        }
        __syncthreads();
    }

    if (tid < 4) {
        const int q = tid;
        float mx = lgts[q][0];
#pragma unroll
        for (int c = 1; c < CC; ++c) mx = fmaxf(mx, lgts[q][c]);
        float e[CC], s = 0.f;
#pragma unroll
        for (int c = 0; c < CC; ++c) { e[c] = expf(lgts[q][c] - mx); s += e[c]; }
        const float inv = 1.f / s;
#pragma unroll
        for (int c = 0; c < CC; ++c) out[(4 * m + q) * CC + c] = e[c] * inv;
    }

    float v = dacc;
    for (int o = 32; o > 0; o >>= 1) v += __shfl_down(v, o);
    if (lane == 0) red[wv] = v;
    __syncthreads();
    if (tid == 0) {
        float s = 0.f;
#pragma unroll
        for (int w = 0; w < 16; ++w) s += red[w];
        atomicAdd(delta_out, s);
    }
}

extern "C" void kernel_launch(void* const* d_in, const int* in_sizes, int n_in,
                              void* d_out, int out_size, void* d_ws, size_t ws_size,
                              hipStream_t stream) {
    const float* x       = (const float*)d_in[0];   // (1024, 128)
    const float* W       = (const float*)d_in[1];   // (2047, 34314)
    const float* heights = (const float*)d_in[2];   // (2047,)

    float* out   = (float*)d_out;
    float* delta = (float*)d_out + LN * CC;
    float* eff   = (float*)d_ws;                    // 32 * 34314 floats = 4.4 MB
    float* ws_h0 = (float*)d_ws + 32 * DD;          // 1024*128 = 512 KB
    float* ws_h1 = ws_h0 + LN * HH;                 // 512 KB

    init_delta<<<1, 1, 0, stream>>>(delta);
    eff5_kernel<<<256, 1024, 0, stream>>>(W, heights, eff, delta);
    layer_split<OFF_W0, OFF_B0><<<512, 1024, 0, stream>>>(W, eff, x, heights, ws_h0, delta);
    layer_split<OFF_W1, OFF_B1><<<512, 1024, 0, stream>>>(W, eff, ws_h0, heights, ws_h1, delta);
    head_kernel<<<256, 1024, 0, stream>>>(W, eff, ws_h1, heights, out, delta);
}

// Round 17
// 83.382 us; speedup vs baseline: 1.2772x; 1.2772x over previous
//
#include <hip/hip_runtime.h>

#define LN 1024
#define FF 128
#define HH 128
#define CC 10
#define DD 34314
#define DD2 17157
#define CHK 2145          // float2 chunk for eff5 pass (8 chunks cover 17157)
#define OFF_W0 0
#define OFF_B0 16384
#define OFF_W1 16512
#define OFF_B1 32896
#define OFF_W2 33024
#define OFF_B2 34304

__global__ void init_delta(float* delta) { *delta = 0.f; }

__device__ __forceinline__ float invmut(const float* h, int node, int par) {
    return 1.f / fmaxf(fabsf(h[node] - h[par]), 1e-7f);
}

// ---------------- P1: eff5[n5] = sum of rows on path level5(n5) .. root ----------------
__global__ __launch_bounds__(1024) void eff5_kernel(const float* __restrict__ W,
                                                    const float* __restrict__ heights,
                                                    float* __restrict__ eff,
                                                    float* __restrict__ delta_out) {
    const int bid = blockIdx.x;
    const int n5  = bid >> 3;            // 0..31
    const int ck  = bid & 7;             // chunk
    const int tid = threadIdx.x, lane = tid & 63, wv = tid >> 6;

    int p[6];
    p[0] = 31 + n5;
#pragma unroll
    for (int k = 1; k < 6; ++k) p[k] = (p[k - 1] - 1) >> 1;   // p[5] = 0 (root)

    const float2* S[6];
#pragma unroll
    for (int k = 0; k < 6; ++k) S[k] = reinterpret_cast<const float2*>(W + (size_t)p[k] * DD);
    float2* E = reinterpret_cast<float2*>(eff + (size_t)n5 * DD);

    float wgt[6];
#pragma unroll
    for (int k = 0; k < 5; ++k)
        wgt[k] = ((n5 & ((1 << k) - 1)) == 0) ? invmut(heights, p[k], p[k + 1]) : 0.f;
    wgt[5] = 0.f;                        // root: squares via sacc
    const float sqm = (n5 == 0) ? 1.f : 0.f;

    float dacc = 0.f, sacc = 0.f;
    const int lo = ck * CHK;
    const int hi = min(lo + CHK, DD2);
#pragma unroll 1
    for (int i = lo + tid; i < hi; i += 1024) {
        float ex = 0.f, ey = 0.f;
#pragma unroll
        for (int k = 0; k < 6; ++k) {
            const float2 w = S[k][i];
            ex += w.x; ey += w.y;
            dacc += (fabsf(w.x) + fabsf(w.y)) * wgt[k];
            if (k == 5) sacc += w.x * w.x + w.y * w.y;
        }
        E[i] = make_float2(ex, ey);
    }

    __shared__ float red[16];
    float v = dacc + sacc * sqm;
    for (int o = 32; o > 0; o >>= 1) v += __shfl_down(v, o);
    if (lane == 0) red[wv] = v;
    __syncthreads();
    if (tid == 0) {
        float s = 0.f;
#pragma unroll
        for (int w = 0; w < 16; ++w) s += red[w];
        atomicAdd(delta_out, s);
    }
}

// ---------------- P2: 10-stream fused kernel (R14, unroll 2 — session best) ----------------
__global__ __launch_bounds__(1024, 4)
__attribute__((amdgpu_waves_per_eu(4, 4)))
void fused_kernel(const float* __restrict__ W,
                  const float* __restrict__ eff,
                  const float* __restrict__ x,
                  const float* __restrict__ heights,
                  float* __restrict__ out,
                  float* __restrict__ delta_out) {
    const int bid  = blockIdx.x;
    const int m    = ((bid & 7) << 5) | (bid >> 3);   // XCD-chunked bijection (256 = 8*32)
    const int tid  = threadIdx.x;
    const int lane = tid & 63;
    const int wv   = tid >> 6;          // 0..15 : f-range [8*wv, 8*wv+8)
    const int j2   = lane;              // column pair (2*j2, 2*j2+1)

    const int l8 = 255 + m;
    const int l7 = (l8 - 1) >> 1;
    const int l6 = (l7 - 1) >> 1;
    const int l5 = (l6 - 1) >> 1;

    const float* RE = eff + (size_t)(m >> 3) * DD;
    const float* RP[3];
    RP[0] = W + (size_t)l8 * DD;
    RP[1] = W + (size_t)l7 * DD;
    RP[2] = W + (size_t)l6 * DD;
    const int n9a = 511 + 2 * m, n9b = n9a + 1;
    const float* RA[2];
    RA[0] = W + (size_t)n9a * DD;
    RA[1] = W + (size_t)n9b * DD;
    const float* RB[4];
#pragma unroll
    for (int q = 0; q < 4; ++q) RB[q] = W + (size_t)(1023 + 4 * m + q) * DD;

    float wgtP[3];
    wgtP[0] = invmut(heights, l8, l7);                       // unique per block
    wgtP[1] = ((m & 1) == 0) ? invmut(heights, l7, l6) : 0.f;
    wgtP[2] = ((m & 3) == 0) ? invmut(heights, l6, l5) : 0.f;
    float wgtA[2];
    wgtA[0] = invmut(heights, n9a, l8);
    wgtA[1] = invmut(heights, n9b, l8);
    float wgtB[4];
#pragma unroll
    for (int q = 0; q < 4; ++q)
        wgtB[q] = invmut(heights, 1023 + 4 * m + q, (q < 2) ? n9a : n9b);

    __shared__ float ins[4][HH];         // current layer input per leaf
    __shared__ float part[4][16][HH];    // matvec partials [leaf][wave][col]  (32 KB)
    __shared__ float lgts[4][CC];
    __shared__ float red[16];

    if (tid < 512) { const int q = tid >> 7, t = tid & 127; ins[q][t] = x[(4 * m + q) * FF + t]; }
    if (tid < 4 * CC) ((float*)lgts)[tid] = 0.f;

    float dacc = 0.f;
    __syncthreads();

    // ---------------- layers 0 and 1 (128 -> 128) ----------------
#pragma unroll
    for (int layer = 0; layer < 2; ++layer) {
        const int offW = layer ? OFF_W1 : OFF_W0;
        const int offB = layer ? OFF_B1 : OFF_B0;
        const float2* SE = reinterpret_cast<const float2*>(RE + offW);
        const float2* SP[3];
#pragma unroll
        for (int r = 0; r < 3; ++r) SP[r] = reinterpret_cast<const float2*>(RP[r] + offW);
        const float2* SA[2];
#pragma unroll
        for (int r = 0; r < 2; ++r) SA[r] = reinterpret_cast<const float2*>(RA[r] + offW);
        const float2* SB[4];
#pragma unroll
        for (int r = 0; r < 4; ++r) SB[r] = reinterpret_cast<const float2*>(RB[r] + offW);

        float yx[4], yy[4];
#pragma unroll
        for (int q = 0; q < 4; ++q) { yx[q] = 0.f; yy[q] = 0.f; }

#pragma unroll 2
        for (int i = 0; i < 8; ++i) {
            const int f   = (wv << 3) + i;
            const int off = (f << 6) + j2;
            const float2 we = SE[off];
            float ex = we.x, ey = we.y;
#pragma unroll
            for (int k = 0; k < 3; ++k) {
                const float2 w = SP[k][off];
                ex += w.x; ey += w.y;
                dacc += (fabsf(w.x) + fabsf(w.y)) * wgtP[k];
            }
            const float2 wa0 = SA[0][off];
            const float2 wa1 = SA[1][off];
            dacc += (fabsf(wa0.x) + fabsf(wa0.y)) * wgtA[0];
            dacc += (fabsf(wa1.x) + fabsf(wa1.y)) * wgtA[1];
#pragma unroll
            for (int q = 0; q < 4; ++q) {
                const float2 wb = SB[q][off];
                dacc += (fabsf(wb.x) + fabsf(wb.y)) * wgtB[q];
                const float2 wa = (q < 2) ? wa0 : wa1;
                const float xv = ins[q][f];
                yx[q] += xv * (ex + wa.x + wb.x);
                yy[q] += xv * (ey + wa.y + wb.y);
            }
        }
#pragma unroll
        for (int q = 0; q < 4; ++q)
            *reinterpret_cast<float2*>(&part[q][wv][2 * j2]) = make_float2(yx[q], yy[q]);
        __syncthreads();

        if (tid < 512) {
            const int q = tid >> 7, col = tid & 127;   // q uniform per wave
            const float p0 = RP[0][offB + col];
            const float p1 = RP[1][offB + col];
            const float p2 = RP[2][offB + col];
            float eb = RE[offB + col] + p0 + p1 + p2;
            if (q == 0)
                dacc += fabsf(p0) * wgtP[0] + fabsf(p1) * wgtP[1] + fabsf(p2) * wgtP[2];
            const float a0 = RA[0][offB + col];
            const float a1 = RA[1][offB + col];
            if (q == 0) dacc += fabsf(a0) * wgtA[0];
            if (q == 2) dacc += fabsf(a1) * wgtA[1];
            const float bq = RB[q][offB + col];
            dacc += fabsf(bq) * wgtB[q];
            float s = eb + ((q < 2) ? a0 : a1) + bq;
#pragma unroll
            for (int w = 0; w < 16; ++w) s += part[q][w][col];
            ins[q][col] = fmaxf(s, 0.f);
        }
        __syncthreads();
    }

    // ---------------- layer 2 (128 -> 10) ----------------
    {
        const float2* SE = reinterpret_cast<const float2*>(RE + OFF_W2);
        const float2* SP[3];
#pragma unroll
        for (int r = 0; r < 3; ++r) SP[r] = reinterpret_cast<const float2*>(RP[r] + OFF_W2);
        const float2* SA[2];
#pragma unroll
        for (int r = 0; r < 2; ++r) SA[r] = reinterpret_cast<const float2*>(RA[r] + OFF_W2);
        const float2* SB[4];
#pragma unroll
        for (int r = 0; r < 4; ++r) SB[r] = reinterpret_cast<const float2*>(RB[r] + OFF_W2);
        if (tid < 640) {                 // 640 float2 = 1280 weights per row
            const int h  = tid / 5;
            const int c0 = (tid - 5 * h) * 2;
            const float2 we = SE[tid];
            float ex = we.x, ey = we.y;
#pragma unroll
            for (int k = 0; k < 3; ++k) {
                const float2 w = SP[k][tid];
                ex += w.x; ey += w.y;
                dacc += (fabsf(w.x) + fabsf(w.y)) * wgtP[k];
            }
            const float2 wa0 = SA[0][tid];
            const float2 wa1 = SA[1][tid];
            dacc += (fabsf(wa0.x) + fabsf(wa0.y)) * wgtA[0];
            dacc += (fabsf(wa1.x) + fabsf(wa1.y)) * wgtA[1];
#pragma unroll
            for (int q = 0; q < 4; ++q) {
                const float2 wb = SB[q][tid];
                dacc += (fabsf(wb.x) + fabsf(wb.y)) * wgtB[q];
                const float2 wa = (q < 2) ? wa0 : wa1;
                const float hv = ins[q][h];
                atomicAdd(&lgts[q][c0],     hv * (ex + wa.x + wb.x));
                atomicAdd(&lgts[q][c0 + 1], hv * (ey + wa.y + wb.y));
            }
        }
        __syncthreads();
        if (tid < CC) {
            const float p0 = RP[0][OFF_B2 + tid];
            const float p1 = RP[1][OFF_B2 + tid];
            const float p2 = RP[2][OFF_B2 + tid];
            float eb = RE[OFF_B2 + tid] + p0 + p1 + p2;
            dacc += fabsf(p0) * wgtP[0] + fabsf(p1) * wgtP[1] + fabsf(p2) * wgtP[2];
            const float a0 = RA[0][OFF_B2 + tid];
            const float a1 = RA[1][OFF_B2 + tid];
            dacc += fabsf(a0) * wgtA[0] + fabsf(a1) * wgtA[1];
#pragma unroll
            for (int q = 0; q < 4; ++q) {
                const float bq = RB[q][OFF_B2 + tid];
                dacc += fabsf(bq) * wgtB[q];
                lgts[q][tid] += eb + ((q < 2) ? a0 : a1) + bq;
            }
        }
        __syncthreads();
    }

    // ---------------- softmax (one thread per leaf) ----------------
    if (tid < 4) {
        const int q = tid;
        float mx = lgts[q][0];
#pragma unroll
        for (int c = 1; c < CC; ++c) mx = fmaxf(mx, lgts[q][c]);
        float e[CC], s = 0.f;
#pragma unroll
        for (int c = 0; c < CC; ++c) { e[c] = expf(lgts[q][c] - mx); s += e[c]; }
        const float inv = 1.f / s;
#pragma unroll
        for (int c = 0; c < CC; ++c) out[(4 * m + q) * CC + c] = e[c] * inv;
    }

    // ---------------- delta reduce ----------------
    float v = dacc;
    for (int o = 32; o > 0; o >>= 1) v += __shfl_down(v, o);
    if (lane == 0) red[wv] = v;
    __syncthreads();
    if (tid == 0) {
        float s = 0.f;
#pragma unroll
        for (int w = 0; w < 16; ++w) s += red[w];
        atomicAdd(delta_out, s);
    }
}

extern "C" void kernel_launch(void* const* d_in, const int* in_sizes, int n_in,
                              void* d_out, int out_size, void* d_ws, size_t ws_size,
                              hipStream_t stream) {
    const float* x       = (const float*)d_in[0];   // (1024, 128)
    const float* W       = (const float*)d_in[1];   // (2047, 34314)
    const float* heights = (const float*)d_in[2];   // (2047,)

    float* out   = (float*)d_out;
    float* delta = (float*)d_out + LN * CC;
    float* eff   = (float*)d_ws;                    // 32 * 34314 * 4 B = 4.4 MB

    init_delta<<<1, 1, 0, stream>>>(delta);
    eff5_kernel<<<256, 1024, 0, stream>>>(W, heights, eff, delta);
    fused_kernel<<<256, 1024, 0, stream>>>(W, eff, x, heights, out, delta);
}